// Round 10
// baseline (373.758 us; speedup 1.0000x reference)
//
#include <hip/hip_runtime.h>
#include <cstdint>
#include <cstddef>

// ---------------- constants ----------------
constexpr int T_SEQ = 4096;
constexpr int NH    = 16;
constexpr int HD    = 128;
constexpr int DIM   = 2048;
constexpr int HDIM  = 2048;   // NH*HD

typedef __attribute__((ext_vector_type(8)))  short  short8;
typedef __attribute__((ext_vector_type(4)))  float  f32x4;
typedef __attribute__((ext_vector_type(16))) float  f32x16;
typedef __attribute__((ext_vector_type(8)))  unsigned short u16x8;
typedef __attribute__((ext_vector_type(4)))  unsigned short u16x4;
typedef __attribute__((ext_vector_type(4)))  unsigned uint4v;
typedef __attribute__((ext_vector_type(2)))  int int2v;

__device__ __forceinline__ unsigned short f2bf(float f) {
  unsigned u = __float_as_uint(f);
  return (unsigned short)((u + 0x7FFFu + ((u >> 16) & 1u)) >> 16);  // RNE
}
__device__ __forceinline__ float bf2f(unsigned short h) {
  return __uint_as_float(((unsigned)h) << 16);
}
__device__ __forceinline__ void gload_lds16(const void* g, void* l) {
  __builtin_amdgcn_global_load_lds((const __attribute__((address_space(1))) void*)g,
                                   (__attribute__((address_space(3))) void*)l, 16, 0, 0);
}
__device__ __forceinline__ int2v plswap(int a, int b) {
  return __builtin_amdgcn_permlane32_swap(a, b, false, false);
}
__device__ __forceinline__ void bar() {           // raw barrier: no implicit vmcnt(0)
  asm volatile("" ::: "memory");
  __builtin_amdgcn_s_barrier();
  asm volatile("" ::: "memory");
}
#define VMCNT(n) asm volatile("s_waitcnt vmcnt(" #n ")" ::: "memory")

// ---------------- fp32 -> bf16 convert ----------------
__global__ __launch_bounds__(256) void cvt_f32_bf16(const float* __restrict__ in,
                                                    unsigned short* __restrict__ out, int n4) {
  int i = blockIdx.x * 256 + threadIdx.x;
  if (i < n4) {
    float4 v = ((const float4*)in)[i];
    u16x4 o; o.x = f2bf(v.x); o.y = f2bf(v.y); o.z = f2bf(v.z); o.w = f2bf(v.w);
    ((u16x4*)out)[i] = o;
  }
}

// ---------------- RoPE tables ----------------
__global__ __launch_bounds__(256) void rope_tables(float* __restrict__ cosT, float* __restrict__ sinT) {
  int idx = blockIdx.x * 256 + threadIdx.x;           // T_SEQ*64
  if (idx >= T_SEQ * 64) return;
  int t = idx >> 6, i = idx & 63;
  float ang = (i < 32) ? exp2f(-10.0f * (float)i / 31.0f) : 0.0f;  // (1/1024)^(i/31)
  float th = (float)t * ang;
  cosT[idx] = cosf(th);
  sinT[idx] = sinf(th);
}

// ---------------- GEMM: C = A * B^T (deep-pipelined, T2+T3+T4+T5) ----------------
template <int MODE>
__global__ __launch_bounds__(512) void gemm256(const unsigned short* __restrict__ A,
                                               const unsigned short* __restrict__ B,
                                               int K, unsigned short* __restrict__ outb,
                                               float* __restrict__ outf, int N) {
  __shared__ __align__(16) char SM[3 * 49152];   // 144KB: 3 x [A 16KB | B 32KB]
  const int tid = threadIdx.x, w = tid >> 6, lane = tid & 63;
  const int wm = w >> 2, wn = w & 3;
  const int lr = lane >> 4, lc = lane & 15, lc7 = lc & 7;
  const int cpx = gridDim.x >> 3;
  const int idx = (blockIdx.x & 7) * cpx + (blockIdx.x >> 3);
  const int m0 = (idx & 31) * 128, n0 = (idx >> 5) * 256;

  const int arow = lane >> 3;
  const int xcol = ((lane & 7) ^ ((lane >> 3) & 7)) * 8;  // pre-swizzled source col

  auto stageA = [&](int buf, int t) {
    char* base = SM + buf * 49152;
#pragma unroll
    for (int i = 0; i < 2; i++) {
      int c = w + i * 8;
      gload_lds16(A + (size_t)(m0 + c * 8 + arow) * K + t * 64 + xcol, base + c * 1024);
    }
  };
  auto stageB0 = [&](int buf, int t) {
    char* base = SM + buf * 49152 + 16384;
    gload_lds16(B + (size_t)(n0 + w * 8 + arow) * K + t * 64 + xcol, base + w * 1024);
  };
  auto stageB1 = [&](int buf, int t) {
    char* base = SM + buf * 49152 + 16384;
#pragma unroll
    for (int i = 1; i < 4; i++) {
      int c = w + i * 8;
      gload_lds16(B + (size_t)(n0 + c * 8 + arow) * K + t * 64 + xcol, base + c * 1024);
    }
  };

  f32x4 acc[4][4] = {};
  const int NT = K >> 6;

  stageA(0, 0); stageB0(0, 0); stageB1(0, 0);
  stageA(1, 1); stageB0(1, 1); stageB1(1, 1);
  VMCNT(6);
  bar();

#pragma unroll 1
  for (int t = 0; t < NT; t++) {
    const int c = t % 3, s = (t + 2) % 3;
    const bool st = (t + 2) < NT;
    const char* Ab = SM + c * 49152;
    const char* Bb = Ab + 16384;

    short8 a[4], b[4];
#pragma unroll
    for (int mi = 0; mi < 4; mi++)
      a[mi] = *(const short8*)(Ab + (wm * 64 + mi * 16 + lc) * 128 + ((0 + lr) ^ lc7) * 16);
#pragma unroll
    for (int ni = 0; ni < 4; ni++)
      b[ni] = *(const short8*)(Bb + (wn * 64 + ni * 16 + lc) * 128 + ((0 + lr) ^ lc7) * 16);
    if (st) { stageA(s, t + 2); stageB0(s, t + 2); }
    bar();
    __builtin_amdgcn_s_setprio(1);
#pragma unroll
    for (int mi = 0; mi < 4; mi++)
#pragma unroll
      for (int ni = 0; ni < 4; ni++)
        acc[mi][ni] = __builtin_amdgcn_mfma_f32_16x16x32_bf16(a[mi], b[ni], acc[mi][ni], 0, 0, 0);
    __builtin_amdgcn_s_setprio(0);
    bar();

#pragma unroll
    for (int mi = 0; mi < 4; mi++)
      a[mi] = *(const short8*)(Ab + (wm * 64 + mi * 16 + lc) * 128 + ((4 + lr) ^ lc7) * 16);
#pragma unroll
    for (int ni = 0; ni < 4; ni++)
      b[ni] = *(const short8*)(Bb + (wn * 64 + ni * 16 + lc) * 128 + ((4 + lr) ^ lc7) * 16);
    if (st) stageB1(s, t + 2);
    if (st) { VMCNT(6); } else { VMCNT(0); }
    bar();
    __builtin_amdgcn_s_setprio(1);
#pragma unroll
    for (int mi = 0; mi < 4; mi++)
#pragma unroll
      for (int ni = 0; ni < 4; ni++)
        acc[mi][ni] = __builtin_amdgcn_mfma_f32_16x16x32_bf16(a[mi], b[ni], acc[mi][ni], 0, 0, 0);
    __builtin_amdgcn_s_setprio(0);
    bar();
  }

#pragma unroll
  for (int mi = 0; mi < 4; mi++)
#pragma unroll
    for (int ni = 0; ni < 4; ni++)
#pragma unroll
      for (int r = 0; r < 4; r++) {
        int t = m0 + wm * 64 + mi * 16 + lr * 4 + r;
        int n = n0 + wn * 64 + ni * 16 + lc;
        float v = acc[mi][ni][r];
        if (MODE == 0) {
          int cc = n >> 11, e = n & 2047, h = e >> 7, d = e & 127;
          outb[(((size_t)cc * NH + h) * T_SEQ + t) * HD + d] = f2bf(v);
        } else {
          outf[(size_t)t * N + n] = v;
        }
      }
}

// ---------------- RMSNorm + RoPE (in-place on q,k; layout [c][h][t][d]) ----------------
__global__ __launch_bounds__(256) void norm_rope(unsigned short* __restrict__ qkvb,
                                                 const float* __restrict__ cosT,
                                                 const float* __restrict__ sinT) {
  int r = blockIdx.x * 4 + (threadIdx.x >> 6);   // row over [c][h][t], c in {0,1}
  int lane = threadIdx.x & 63;
  int t = r % T_SEQ;
  unsigned short* row = qkvb + (size_t)r * HD;
  float f1 = bf2f(row[lane]), f2 = bf2f(row[lane + 64]);
  float ss = f1 * f1 + f2 * f2;
#pragma unroll
  for (int off = 32; off; off >>= 1) ss += __shfl_xor(ss, off, 64);
  float rs = rsqrtf(ss * (1.0f / 128.0f) + 1e-6f);
  f1 *= rs; f2 *= rs;
  float c_ = cosT[t * 64 + lane], s_ = sinT[t * 64 + lane];
  row[lane]      = f2bf(f1 * c_ + f2 * s_);
  row[lane + 64] = f2bf(-f1 * s_ + f2 * c_);
}

// ---------------- v' = l0*v + l1*ve, transposed to v_t[h][d][t] ----------------
__global__ __launch_bounds__(256) void vmix_transpose(const unsigned short* __restrict__ vb,
                                                      const float* __restrict__ ve,
                                                      const float* __restrict__ lam,
                                                      unsigned short* __restrict__ vt) {
  __shared__ float tile[64][65];
  const int h = blockIdx.z, t0 = blockIdx.x * 64, d0 = blockIdx.y * 64;
  const float l0 = lam[0], l1 = lam[1];
  const int tid = threadIdx.x;
  const int tl = tid >> 4, dl4 = (tid & 15) * 4;
#pragma unroll
  for (int i = 0; i < 4; i++) {
    int t_local = tl + i * 16;
    int t = t0 + t_local;
    const unsigned short* vp = vb + ((size_t)h * T_SEQ + t) * HD + d0 + dl4;
    const float* vep = ve + (size_t)t * HDIM + h * HD + d0 + dl4;
    u16x4 vv = *(const u16x4*)vp;
    float4 vef = *(const float4*)vep;
    tile[t_local][dl4 + 0] = l0 * bf2f(vv.x) + l1 * vef.x;
    tile[t_local][dl4 + 1] = l0 * bf2f(vv.y) + l1 * vef.y;
    tile[t_local][dl4 + 2] = l0 * bf2f(vv.z) + l1 * vef.z;
    tile[t_local][dl4 + 3] = l0 * bf2f(vv.w) + l1 * vef.w;
  }
  __syncthreads();
#pragma unroll
  for (int i = 0; i < 2; i++) {
    int idx = tid + i * 256;
    int d_local = idx >> 3, tloc = (idx & 7) * 8;
    u16x8 o;
#pragma unroll
    for (int j = 0; j < 8; j++) o[j] = f2bf(tile[tloc + j][d_local]);
    *(u16x8*)(vt + ((size_t)h * HD + d0 + d_local) * T_SEQ + t0 + tloc) = o;
  }
}

// ---------------- flash attention pass 1: split-KV partials ----------------
// 256 threads / 4 warps, QBLK=128 (warp owns 32 q), KVBLK=64, swapped-operand 32x32x16.
// Block (h, pr, par) processes q-tiles (31-pr) then (pr), using kv tiles of parity par:
// t = par, par+2, ..., 2*qt+par  ->  ng = qt+1 tiles each parity (R9 BUG was ng~qt/2:
// q-tiles are 128 rows = 2 kv-tiles, so the diagonal is kv-tile 2qt+1, not qt).
// Every block runs exactly 33 tiles. Writes unnormalized partial O (bf16) + (m,l).
// Grid 512 = 2 blocks/CU -> 2 waves/SIMD without the 512-thread 128-VGPR spill trap.
__global__ __launch_bounds__(256) void attn_part(const unsigned short* __restrict__ qb,
                                                 const unsigned short* __restrict__ kb,
                                                 const unsigned short* __restrict__ vt,
                                                 unsigned short* __restrict__ part,
                                                 float* __restrict__ ml) {
  __shared__ __align__(16) char SMEM[65536];    // K 2x16KB | V 2x16KB
  const int bid = blockIdx.x;
  const int h   = bid & 15;                     // bid%8 = h%8 -> head pinned to one XCD
  const int pr  = (bid >> 4) & 15;
  const int par = bid >> 8;                     // kv-tile parity
  const int tid = threadIdx.x, wq = tid >> 6, lane = tid & 63;
  const int l31 = lane & 31, hi = lane >> 5, r7 = l31 & 7;
  const unsigned short* qh = qb + (size_t)h * T_SEQ * HD;
  const unsigned short* kh = kb + (size_t)h * T_SEQ * HD;
  const unsigned short* vh = vt + (size_t)h * HD * T_SEQ;

  char* Kbase = SMEM;
  char* Vbase = SMEM + 32768;

  const int kcrow = lane >> 4, kcol16 = lane & 15;   // K staging: 4 rows / 1KB chunk
  const int vcrow = lane >> 3, vslot0 = lane & 7;    // V staging: 8 rows / 1KB chunk

  auto STAGE = [&](int buf, int t) {                 // t = global kv tile index
#pragma unroll
    for (int i = 0; i < 4; i++) {
      int krow = (wq * 4 + i) * 4 + kcrow;
      int kcol = (kcol16 ^ (krow & 7)) * 8;          // pre-swizzled source (rule #21)
      gload_lds16(kh + (size_t)(t * 64 + krow) * HD + kcol,
                  Kbase + buf * 16384 + (wq * 4 + i) * 1024);
      int vrow = (wq * 4 + i) * 8 + vcrow;
      int vcol = (vslot0 ^ (vrow & 7)) * 8;
      gload_lds16(vh + (size_t)vrow * T_SEQ + t * 64 + vcol,
                  Vbase + buf * 16384 + (wq * 4 + i) * 1024);
    }
  };

  const float SCL2E = 0.088388347648318447f * 1.44269504f;  // 1/sqrt(128) * log2(e)

#pragma unroll 1
  for (int which = 0; which < 2; ++which) {
    const int qt = which ? pr : (31 - pr);     // heavy tile first
    const int ng = qt + 1;                     // parity-par kv tiles up to 2qt+par
    const int q_row = qt * 128 + wq * 32 + l31;

    short8 qf[8];                              // B-frag: Q[q_row][16dk + 8hi + 0..7]
#pragma unroll
    for (int dk = 0; dk < 8; dk++)
      qf[dk] = *(const short8*)(qh + (size_t)q_row * HD + dk * 16 + hi * 8);

    f32x16 accO[4] = {};                       // O^T: col=q, rows d (4 tiles of 32)
    float m_r = -1e30f, l_r = 0.0f;

    __syncthreads();                           // all warps done reading prev LDS
    STAGE(0, par);

#pragma unroll 1
    for (int it = 0; it < ng; it++) {
      const int t = 2 * it + par;              // this block's kv tile
      const int cur = it & 1;
      VMCNT(0);                                // stage(cur) landed (only outstanding)
      __syncthreads();
      if (it + 1 < ng) STAGE(cur ^ 1, t + 2);  // prefetch under compute

      // ---- S^T = K Q^T : 2 kv-subtiles x 8 d-steps ----
      f32x16 accS0 = {}, accS1 = {};
      const char* Kb = Kbase + cur * 16384 + l31 * 256;
      __builtin_amdgcn_s_setprio(1);
#pragma unroll
      for (int dk = 0; dk < 8; dk++) {
        int sl = ((2 * dk + hi) ^ r7) * 16;
        short8 k0 = *(const short8*)(Kb + sl);
        short8 k1 = *(const short8*)(Kb + 32 * 256 + sl);
        accS0 = __builtin_amdgcn_mfma_f32_32x32x16_bf16(k0, qf[dk], accS0, 0, 0, 0);
        accS1 = __builtin_amdgcn_mfma_f32_32x32x16_bf16(k1, qf[dk], accS1, 0, 0, 0);
      }
      __builtin_amdgcn_s_setprio(0);

      // ---- scale + causal mask; lane holds P[q_row][kv], kv = 64t+(r&3)+8(r>>2)+4hi ----
      float p[32];
      const bool need_mask = (t * 64 + 63) > (qt * 128 + wq * 32);
      if (need_mask) {
#pragma unroll
        for (int r = 0; r < 16; r++) {
          int kv0 = t * 64 + (r & 3) + 8 * (r >> 2) + 4 * hi;
          p[r]      = (kv0      > q_row) ? -1e30f : accS0[r] * SCL2E;
          p[16 + r] = (kv0 + 32 > q_row) ? -1e30f : accS1[r] * SCL2E;
        }
      } else {
#pragma unroll
        for (int r = 0; r < 16; r++) { p[r] = accS0[r] * SCL2E; p[16 + r] = accS1[r] * SCL2E; }
      }

      // ---- row max: in-register tree + one cross-half permlane ----
      float t16[16];
#pragma unroll
      for (int i = 0; i < 16; i++) t16[i] = fmaxf(p[i], p[i + 16]);
#pragma unroll
      for (int st = 8; st >= 1; st >>= 1)
#pragma unroll
        for (int i = 0; i < st; i++) t16[i] = fmaxf(t16[i], t16[i + st]);
      int2v mr_ = plswap(__float_as_int(t16[0]), __float_as_int(t16[0]));
      float mx = fmaxf(t16[0], __int_as_float(hi ? mr_.x : mr_.y));

      // ---- defer-max (T13): rescale only when max grows past THR ----
      if (__any(mx > m_r + 8.0f)) {
        float mn = fmaxf(m_r, mx);
        float alpha = exp2f(m_r - mn);
        m_r = mn; l_r *= alpha;
#pragma unroll
        for (int dt = 0; dt < 4; dt++)
#pragma unroll
          for (int r = 0; r < 16; r++) accO[dt][r] *= alpha;
      }

      // ---- exp + row sum ----
#pragma unroll
      for (int i = 0; i < 32; i++) p[i] = exp2f(p[i] - m_r);
      float s16[16];
#pragma unroll
      for (int i = 0; i < 16; i++) s16[i] = p[i] + p[i + 16];
#pragma unroll
      for (int st = 8; st >= 1; st >>= 1)
#pragma unroll
        for (int i = 0; i < st; i++) s16[i] += s16[i + st];
      int2v sr_ = plswap(__float_as_int(s16[0]), __float_as_int(s16[0]));
      l_r += s16[0] + __int_as_float(hi ? sr_.x : sr_.y);

      // ---- pack P to bf16 pairs: pk[octet][c] = (kv=8o+4hi+2c, +1) ----
      unsigned pk[8][2];
#pragma unroll
      for (int o = 0; o < 8; o++)
#pragma unroll
        for (int c = 0; c < 2; c++) {
          float lo = p[(o >> 2) * 16 + (o & 3) * 4 + 2 * c];
          float hi_ = p[(o >> 2) * 16 + (o & 3) * 4 + 2 * c + 1];
          asm("v_cvt_pk_bf16_f32 %0, %1, %2" : "=v"(pk[o][c]) : "v"(lo), "v"(hi_));
        }

      // ---- PV: O^T += V^T P^T ; B-frag(ks) via permlane32_swap ----
      const char* Vb = Vbase + cur * 16384 + l31 * 128;
#pragma unroll
      for (int ks = 0; ks < 4; ks++) {
        int2v s0 = plswap((int)pk[2 * ks][0], (int)pk[2 * ks + 1][0]);
        int2v s1 = plswap((int)pk[2 * ks][1], (int)pk[2 * ks + 1][1]);
        uint4v pw;
        pw.x = (unsigned)s0.x;   // kv 16ks+8hi+{0,1}
        pw.y = (unsigned)s1.x;   // +{2,3}
        pw.z = (unsigned)s0.y;   // +{4,5}
        pw.w = (unsigned)s1.y;   // +{6,7}
        short8 pb = __builtin_bit_cast(short8, pw);
        int sl = ((2 * ks + hi) ^ r7) * 16;
        __builtin_amdgcn_s_setprio(1);
#pragma unroll
        for (int dt = 0; dt < 4; dt++) {
          short8 vf = *(const short8*)(Vb + dt * 32 * 128 + sl);
          accO[dt] = __builtin_amdgcn_mfma_f32_32x32x16_bf16(vf, pb, accO[dt], 0, 0, 0);
        }
        __builtin_amdgcn_s_setprio(0);
      }
    }

    // ---- write unnormalized partial + (m, l) ----
    unsigned short* pp = part + (size_t)par * T_SEQ * HDIM + (size_t)q_row * HDIM + h * HD;
#pragma unroll
    for (int dt = 0; dt < 4; dt++)
#pragma unroll
      for (int q4 = 0; q4 < 4; q4++) {
        int dbase = 32 * dt + 8 * q4 + 4 * hi;
        u16x4 o;
#pragma unroll
        for (int j = 0; j < 4; j++) o[j] = f2bf(accO[dt][q4 * 4 + j]);
        *(u16x4*)(pp + dbase) = o;
      }
    if (hi == 0) {
      float* mlp = ml + ((size_t)h * T_SEQ + q_row) * 4 + par * 2;
      mlp[0] = m_r; mlp[1] = l_r;
    }
  }
}

// ---------------- flash attention pass 2: merge parity partials ----------------
// ao[q][h*128+d] = (P0*2^(m0-m) + P1*2^(m1-m)) / (l0*2^(m0-m) + l1*2^(m1-m))
// Fully-masked rows (qt=0,par=1) have m1=-1e30 -> 2^(m1-m)=0 annihilates garbage.
__global__ __launch_bounds__(256) void attn_merge(const unsigned short* __restrict__ part,
                                                  const float* __restrict__ ml,
                                                  unsigned short* __restrict__ ao) {
  int gid = blockIdx.x * 256 + threadIdx.x;     // 4096 q x 256 chunks of 8
  int q = gid >> 8, hd0 = (gid & 255) * 8;
  int h = hd0 >> 7;
  float4 m4 = *(const float4*)(ml + ((size_t)h * T_SEQ + q) * 4);  // m0,l0,m1,l1
  float m  = fmaxf(m4.x, m4.z);
  float se = exp2f(m4.x - m), so = exp2f(m4.z - m);
  float inv = 1.0f / (m4.y * se + m4.w * so);
  u16x8 a = *(const u16x8*)(part + (size_t)q * HDIM + hd0);
  u16x8 b = *(const u16x8*)(part + (size_t)T_SEQ * HDIM + (size_t)q * HDIM + hd0);
  u16x8 o;
#pragma unroll
  for (int j = 0; j < 8; j++)
    o[j] = f2bf((bf2f(a[j]) * se + bf2f(b[j]) * so) * inv);
  *(u16x8*)(ao + (size_t)q * HDIM + hd0) = o;
}

// ---------------- launch ----------------
extern "C" void kernel_launch(void* const* d_in, const int* in_sizes, int n_in,
                              void* d_out, int out_size, void* d_ws, size_t ws_size,
                              hipStream_t stream) {
  const float* x      = (const float*)d_in[0];
  const float* ve     = (const float*)d_in[1];
  const float* lam    = (const float*)d_in[2];
  const float* qkv_w  = (const float*)d_in[3];
  const float* proj_w = (const float*)d_in[4];
  float* out = (float*)d_out;

  char* p = (char*)d_ws;
  float* cosT = (float*)p;            p += (size_t)T_SEQ * 64 * 4;
  float* sinT = (float*)p;            p += (size_t)T_SEQ * 64 * 4;
  unsigned short* xb   = (unsigned short*)p; p += (size_t)T_SEQ * DIM * 2;
  unsigned short* wqb  = (unsigned short*)p; p += (size_t)3 * HDIM * DIM * 2;
  unsigned short* pwb  = (unsigned short*)p; p += (size_t)DIM * HDIM * 2;
  unsigned short* qkvb = (unsigned short*)p; p += (size_t)3 * NH * T_SEQ * HD * 2;
  unsigned short* vtb  = (unsigned short*)p; p += (size_t)NH * HD * T_SEQ * 2;
  unsigned short* aob  = (unsigned short*)p; p += (size_t)T_SEQ * HDIM * 2;
  // partials ALIAS xb+wqb (16+24=40MB, dead after the QKV GEMM; need 32+1MB):
  unsigned short* prt  = xb;
  float* mlb           = (float*)((char*)xb + (size_t)2 * T_SEQ * HDIM * 2);

  cvt_f32_bf16<<<(T_SEQ * DIM / 4 + 255) / 256, 256, 0, stream>>>(x, xb, T_SEQ * DIM / 4);
  cvt_f32_bf16<<<(3 * HDIM * DIM / 4 + 255) / 256, 256, 0, stream>>>(qkv_w, wqb, 3 * HDIM * DIM / 4);
  cvt_f32_bf16<<<(DIM * HDIM / 4 + 255) / 256, 256, 0, stream>>>(proj_w, pwb, DIM * HDIM / 4);
  rope_tables<<<(T_SEQ * 64 + 255) / 256, 256, 0, stream>>>(cosT, sinT);

  // QKV: M=4096 (32 m-blocks), N=6144 (24 n-blocks) -> 768 blocks = 3/CU exactly
  gemm256<0><<<768, 512, 0, stream>>>(xb, wqb, DIM, qkvb, nullptr, 3 * HDIM);
  norm_rope<<<2 * NH * T_SEQ / 4, 256, 0, stream>>>(qkvb, cosT, sinT);
  vmix_transpose<<<dim3(T_SEQ / 64, HD / 64, NH), 256, 0, stream>>>(
      qkvb + (size_t)2 * NH * T_SEQ * HD, ve, lam, vtb);
  // attention: 512 balanced split-KV blocks (2/CU), then elementwise merge
  attn_part<<<512, 256, 0, stream>>>(qkvb, qkvb + (size_t)NH * T_SEQ * HD, vtb, prt, mlb);
  attn_merge<<<T_SEQ * 256 / 256, 256, 0, stream>>>(prt, mlb, aob);
  // proj: M=4096 (32), N=2048 (8 n-blocks) -> 256 blocks = 1/CU exactly
  gemm256<1><<<256, 512, 0, stream>>>(aob, pwb, HDIM, nullptr, out, HDIM);
}

// Round 11
// 372.795 us; speedup vs baseline: 1.0026x; 1.0026x over previous
//
#include <hip/hip_runtime.h>
#include <cstdint>
#include <cstddef>

// ---------------- constants ----------------
constexpr int T_SEQ = 4096;
constexpr int NH    = 16;
constexpr int HD    = 128;
constexpr int DIM   = 2048;
constexpr int HDIM  = 2048;   // NH*HD

typedef __attribute__((ext_vector_type(8)))  short  short8;
typedef __attribute__((ext_vector_type(4)))  float  f32x4;
typedef __attribute__((ext_vector_type(16))) float  f32x16;
typedef __attribute__((ext_vector_type(8)))  unsigned short u16x8;
typedef __attribute__((ext_vector_type(4)))  unsigned short u16x4;
typedef __attribute__((ext_vector_type(4)))  unsigned uint4v;
typedef __attribute__((ext_vector_type(2)))  int int2v;

__device__ __forceinline__ unsigned short f2bf(float f) {
  unsigned u = __float_as_uint(f);
  return (unsigned short)((u + 0x7FFFu + ((u >> 16) & 1u)) >> 16);  // RNE
}
__device__ __forceinline__ float bf2f(unsigned short h) {
  return __uint_as_float(((unsigned)h) << 16);
}
__device__ __forceinline__ void gload_lds16(const void* g, void* l) {
  __builtin_amdgcn_global_load_lds((const __attribute__((address_space(1))) void*)g,
                                   (__attribute__((address_space(3))) void*)l, 16, 0, 0);
}
__device__ __forceinline__ int2v plswap(int a, int b) {
  return __builtin_amdgcn_permlane32_swap(a, b, false, false);
}
__device__ __forceinline__ void bar() {           // raw barrier: no implicit vmcnt(0)
  asm volatile("" ::: "memory");
  __builtin_amdgcn_s_barrier();
  asm volatile("" ::: "memory");
}
#define VMCNT(n) asm volatile("s_waitcnt vmcnt(" #n ")" ::: "memory")

// ---------------- fp32 -> bf16 convert ----------------
__global__ __launch_bounds__(256) void cvt_f32_bf16(const float* __restrict__ in,
                                                    unsigned short* __restrict__ out, int n4) {
  int i = blockIdx.x * 256 + threadIdx.x;
  if (i < n4) {
    float4 v = ((const float4*)in)[i];
    u16x4 o; o.x = f2bf(v.x); o.y = f2bf(v.y); o.z = f2bf(v.z); o.w = f2bf(v.w);
    ((u16x4*)out)[i] = o;
  }
}

// ---------------- RoPE tables ----------------
__global__ __launch_bounds__(256) void rope_tables(float* __restrict__ cosT, float* __restrict__ sinT) {
  int idx = blockIdx.x * 256 + threadIdx.x;           // T_SEQ*64
  if (idx >= T_SEQ * 64) return;
  int t = idx >> 6, i = idx & 63;
  float ang = (i < 32) ? exp2f(-10.0f * (float)i / 31.0f) : 0.0f;  // (1/1024)^(i/31)
  float th = (float)t * ang;
  cosT[idx] = cosf(th);
  sinT[idx] = sinf(th);
}

// ---------------- GEMM: C = A * B^T (deep-pipelined, T2+T3+T4+T5) ----------------
template <int MODE>
__global__ __launch_bounds__(512) void gemm256(const unsigned short* __restrict__ A,
                                               const unsigned short* __restrict__ B,
                                               int K, unsigned short* __restrict__ outb,
                                               float* __restrict__ outf, int N) {
  __shared__ __align__(16) char SM[3 * 49152];   // 144KB: 3 x [A 16KB | B 32KB]
  const int tid = threadIdx.x, w = tid >> 6, lane = tid & 63;
  const int wm = w >> 2, wn = w & 3;
  const int lr = lane >> 4, lc = lane & 15, lc7 = lc & 7;
  const int cpx = gridDim.x >> 3;
  const int idx = (blockIdx.x & 7) * cpx + (blockIdx.x >> 3);
  const int m0 = (idx & 31) * 128, n0 = (idx >> 5) * 256;

  const int arow = lane >> 3;
  const int xcol = ((lane & 7) ^ ((lane >> 3) & 7)) * 8;  // pre-swizzled source col

  auto stageA = [&](int buf, int t) {
    char* base = SM + buf * 49152;
#pragma unroll
    for (int i = 0; i < 2; i++) {
      int c = w + i * 8;
      gload_lds16(A + (size_t)(m0 + c * 8 + arow) * K + t * 64 + xcol, base + c * 1024);
    }
  };
  auto stageB0 = [&](int buf, int t) {
    char* base = SM + buf * 49152 + 16384;
    gload_lds16(B + (size_t)(n0 + w * 8 + arow) * K + t * 64 + xcol, base + w * 1024);
  };
  auto stageB1 = [&](int buf, int t) {
    char* base = SM + buf * 49152 + 16384;
#pragma unroll
    for (int i = 1; i < 4; i++) {
      int c = w + i * 8;
      gload_lds16(B + (size_t)(n0 + c * 8 + arow) * K + t * 64 + xcol, base + c * 1024);
    }
  };

  f32x4 acc[4][4] = {};
  const int NT = K >> 6;

  stageA(0, 0); stageB0(0, 0); stageB1(0, 0);
  stageA(1, 1); stageB0(1, 1); stageB1(1, 1);
  VMCNT(6);
  bar();

#pragma unroll 1
  for (int t = 0; t < NT; t++) {
    const int c = t % 3, s = (t + 2) % 3;
    const bool st = (t + 2) < NT;
    const char* Ab = SM + c * 49152;
    const char* Bb = Ab + 16384;

    short8 a[4], b[4];
#pragma unroll
    for (int mi = 0; mi < 4; mi++)
      a[mi] = *(const short8*)(Ab + (wm * 64 + mi * 16 + lc) * 128 + ((0 + lr) ^ lc7) * 16);
#pragma unroll
    for (int ni = 0; ni < 4; ni++)
      b[ni] = *(const short8*)(Bb + (wn * 64 + ni * 16 + lc) * 128 + ((0 + lr) ^ lc7) * 16);
    if (st) { stageA(s, t + 2); stageB0(s, t + 2); }
    bar();
    __builtin_amdgcn_s_setprio(1);
#pragma unroll
    for (int mi = 0; mi < 4; mi++)
#pragma unroll
      for (int ni = 0; ni < 4; ni++)
        acc[mi][ni] = __builtin_amdgcn_mfma_f32_16x16x32_bf16(a[mi], b[ni], acc[mi][ni], 0, 0, 0);
    __builtin_amdgcn_s_setprio(0);
    bar();

#pragma unroll
    for (int mi = 0; mi < 4; mi++)
      a[mi] = *(const short8*)(Ab + (wm * 64 + mi * 16 + lc) * 128 + ((4 + lr) ^ lc7) * 16);
#pragma unroll
    for (int ni = 0; ni < 4; ni++)
      b[ni] = *(const short8*)(Bb + (wn * 64 + ni * 16 + lc) * 128 + ((4 + lr) ^ lc7) * 16);
    if (st) stageB1(s, t + 2);
    if (st) { VMCNT(6); } else { VMCNT(0); }
    bar();
    __builtin_amdgcn_s_setprio(1);
#pragma unroll
    for (int mi = 0; mi < 4; mi++)
#pragma unroll
      for (int ni = 0; ni < 4; ni++)
        acc[mi][ni] = __builtin_amdgcn_mfma_f32_16x16x32_bf16(a[mi], b[ni], acc[mi][ni], 0, 0, 0);
    __builtin_amdgcn_s_setprio(0);
    bar();
  }

#pragma unroll
  for (int mi = 0; mi < 4; mi++)
#pragma unroll
    for (int ni = 0; ni < 4; ni++)
#pragma unroll
      for (int r = 0; r < 4; r++) {
        int t = m0 + wm * 64 + mi * 16 + lr * 4 + r;
        int n = n0 + wn * 64 + ni * 16 + lc;
        float v = acc[mi][ni][r];
        if (MODE == 0) {
          int cc = n >> 11, e = n & 2047, h = e >> 7, d = e & 127;
          outb[(((size_t)cc * NH + h) * T_SEQ + t) * HD + d] = f2bf(v);
        } else {
          outf[(size_t)t * N + n] = v;
        }
      }
}

// ---------------- RMSNorm + RoPE (in-place on q,k; layout [c][h][t][d]) ----------------
__global__ __launch_bounds__(256) void norm_rope(unsigned short* __restrict__ qkvb,
                                                 const float* __restrict__ cosT,
                                                 const float* __restrict__ sinT) {
  int r = blockIdx.x * 4 + (threadIdx.x >> 6);   // row over [c][h][t], c in {0,1}
  int lane = threadIdx.x & 63;
  int t = r % T_SEQ;
  unsigned short* row = qkvb + (size_t)r * HD;
  float f1 = bf2f(row[lane]), f2 = bf2f(row[lane + 64]);
  float ss = f1 * f1 + f2 * f2;
#pragma unroll
  for (int off = 32; off; off >>= 1) ss += __shfl_xor(ss, off, 64);
  float rs = rsqrtf(ss * (1.0f / 128.0f) + 1e-6f);
  f1 *= rs; f2 *= rs;
  float c_ = cosT[t * 64 + lane], s_ = sinT[t * 64 + lane];
  row[lane]      = f2bf(f1 * c_ + f2 * s_);
  row[lane + 64] = f2bf(-f1 * s_ + f2 * c_);
}

// ---------------- v' = l0*v + l1*ve, transposed to v_t[h][d][t] ----------------
__global__ __launch_bounds__(256) void vmix_transpose(const unsigned short* __restrict__ vb,
                                                      const float* __restrict__ ve,
                                                      const float* __restrict__ lam,
                                                      unsigned short* __restrict__ vt) {
  __shared__ float tile[64][65];
  const int h = blockIdx.z, t0 = blockIdx.x * 64, d0 = blockIdx.y * 64;
  const float l0 = lam[0], l1 = lam[1];
  const int tid = threadIdx.x;
  const int tl = tid >> 4, dl4 = (tid & 15) * 4;
#pragma unroll
  for (int i = 0; i < 4; i++) {
    int t_local = tl + i * 16;
    int t = t0 + t_local;
    const unsigned short* vp = vb + ((size_t)h * T_SEQ + t) * HD + d0 + dl4;
    const float* vep = ve + (size_t)t * HDIM + h * HD + d0 + dl4;
    u16x4 vv = *(const u16x4*)vp;
    float4 vef = *(const float4*)vep;
    tile[t_local][dl4 + 0] = l0 * bf2f(vv.x) + l1 * vef.x;
    tile[t_local][dl4 + 1] = l0 * bf2f(vv.y) + l1 * vef.y;
    tile[t_local][dl4 + 2] = l0 * bf2f(vv.z) + l1 * vef.z;
    tile[t_local][dl4 + 3] = l0 * bf2f(vv.w) + l1 * vef.w;
  }
  __syncthreads();
#pragma unroll
  for (int i = 0; i < 2; i++) {
    int idx = tid + i * 256;
    int d_local = idx >> 3, tloc = (idx & 7) * 8;
    u16x8 o;
#pragma unroll
    for (int j = 0; j < 8; j++) o[j] = f2bf(tile[tloc + j][d_local]);
    *(u16x8*)(vt + ((size_t)h * HD + d0 + d_local) * T_SEQ + t0 + tloc) = o;
  }
}

// ---------------- flash attention pass 1: split-KV partials ----------------
// 256 threads / 4 warps, QBLK=128, KVBLK=64, swapped-operand 32x32x16. Block (h,pr,par)
// processes q-tiles (31-pr) then (pr) over kv tiles t = 2*it+par, it<qt+1 (33 tiles/blk).
// Each 64-kv tile runs as TWO sequential 32-kv substeps {QKT->SM->PV}: halves accS
// (32->16 AGPR) + p (32->16 VGPR) so total arch+acc regs fit <=256/wave -> 2 waves/SIMD
// (gfx950 unified VGPR/AGPR file: R10's 172 arch + ~96 acc = 268 > 256 gave 1 wave/SIMD).
__global__ __launch_bounds__(256) void attn_part(const unsigned short* __restrict__ qb,
                                                 const unsigned short* __restrict__ kb,
                                                 const unsigned short* __restrict__ vt,
                                                 unsigned short* __restrict__ part,
                                                 float* __restrict__ ml) {
  __shared__ __align__(16) char SMEM[65536];    // K 2x16KB | V 2x16KB
  const int bid = blockIdx.x;
  const int h   = bid & 15;                     // bid%8 = h%8 -> head pinned to one XCD
  const int pr  = (bid >> 4) & 15;
  const int par = bid >> 8;                     // kv-tile parity
  const int tid = threadIdx.x, wq = tid >> 6, lane = tid & 63;
  const int l31 = lane & 31, hi = lane >> 5, r7 = l31 & 7;
  const unsigned short* qh = qb + (size_t)h * T_SEQ * HD;
  const unsigned short* kh = kb + (size_t)h * T_SEQ * HD;
  const unsigned short* vh = vt + (size_t)h * HD * T_SEQ;

  char* Kbase = SMEM;
  char* Vbase = SMEM + 32768;

  const int kcrow = lane >> 4, kcol16 = lane & 15;   // K staging: 4 rows / 1KB chunk
  const int vcrow = lane >> 3, vslot0 = lane & 7;    // V staging: 8 rows / 1KB chunk

  auto STAGE = [&](int buf, int t) {                 // t = global kv tile index
#pragma unroll
    for (int i = 0; i < 4; i++) {
      int krow = (wq * 4 + i) * 4 + kcrow;
      int kcol = (kcol16 ^ (krow & 7)) * 8;          // pre-swizzled source (rule #21)
      gload_lds16(kh + (size_t)(t * 64 + krow) * HD + kcol,
                  Kbase + buf * 16384 + (wq * 4 + i) * 1024);
      int vrow = (wq * 4 + i) * 8 + vcrow;
      int vcol = (vslot0 ^ (vrow & 7)) * 8;
      gload_lds16(vh + (size_t)vrow * T_SEQ + t * 64 + vcol,
                  Vbase + buf * 16384 + (wq * 4 + i) * 1024);
    }
  };

  const float SCL2E = 0.088388347648318447f * 1.44269504f;  // 1/sqrt(128) * log2(e)

#pragma unroll 1
  for (int which = 0; which < 2; ++which) {
    const int qt = which ? pr : (31 - pr);     // heavy tile first
    const int ng = qt + 1;                     // parity-par kv tiles up to 2qt+par
    const int q_row = qt * 128 + wq * 32 + l31;

    short8 qf[8];                              // B-frag: Q[q_row][16dk + 8hi + 0..7]
#pragma unroll
    for (int dk = 0; dk < 8; dk++)
      qf[dk] = *(const short8*)(qh + (size_t)q_row * HD + dk * 16 + hi * 8);

    f32x16 accO[4] = {};                       // O^T: col=q, rows d (4 tiles of 32)
    float m_r = -1e30f, l_r = 0.0f;

    __syncthreads();                           // all warps done reading prev LDS
    STAGE(0, par);

#pragma unroll 1
    for (int it = 0; it < ng; it++) {
      const int t = 2 * it + par;              // this block's kv tile
      const int cur = it & 1;
      VMCNT(0);                                // stage(cur) landed (only outstanding)
      __syncthreads();
      if (it + 1 < ng) STAGE(cur ^ 1, t + 2);  // prefetch under compute

      const char* Kb = Kbase + cur * 16384 + l31 * 256;
      const char* Vb = Vbase + cur * 16384 + l31 * 128;
      const bool need_mask = (t * 64 + 63) > (qt * 128 + wq * 32);

      // ---- two 32-kv substeps: QKT -> softmax -> PV (halves live registers) ----
#pragma unroll
      for (int sub = 0; sub < 2; sub++) {
        // QK^T sub: S^T = K_sub Q^T
        f32x16 accS = {};
        const char* Ks = Kb + sub * 32 * 256;
        __builtin_amdgcn_s_setprio(1);
#pragma unroll
        for (int dk = 0; dk < 8; dk++) {
          int sl = ((2 * dk + hi) ^ r7) * 16;
          short8 k0 = *(const short8*)(Ks + sl);
          accS = __builtin_amdgcn_mfma_f32_32x32x16_bf16(k0, qf[dk], accS, 0, 0, 0);
        }
        __builtin_amdgcn_s_setprio(0);

        // scale + causal mask; lane holds P[q_row][kv], kv = 64t+32sub+(r&3)+8(r>>2)+4hi
        float p[16];
        if (need_mask) {
#pragma unroll
          for (int r = 0; r < 16; r++) {
            int kv0 = t * 64 + sub * 32 + (r & 3) + 8 * (r >> 2) + 4 * hi;
            p[r] = (kv0 > q_row) ? -1e30f : accS[r] * SCL2E;
          }
        } else {
#pragma unroll
          for (int r = 0; r < 16; r++) p[r] = accS[r] * SCL2E;
        }

        // row max: tree + one cross-half permlane
        float t8[8];
#pragma unroll
        for (int i = 0; i < 8; i++) t8[i] = fmaxf(p[i], p[i + 8]);
#pragma unroll
        for (int st = 4; st >= 1; st >>= 1)
#pragma unroll
          for (int i = 0; i < st; i++) t8[i] = fmaxf(t8[i], t8[i + st]);
        int2v mr_ = plswap(__float_as_int(t8[0]), __float_as_int(t8[0]));
        float mx = fmaxf(t8[0], __int_as_float(hi ? mr_.x : mr_.y));

        // defer-max (T13): rescale only when max grows past THR
        if (__any(mx > m_r + 8.0f)) {
          float mn = fmaxf(m_r, mx);
          float alpha = exp2f(m_r - mn);
          m_r = mn; l_r *= alpha;
#pragma unroll
          for (int dt = 0; dt < 4; dt++)
#pragma unroll
            for (int r = 0; r < 16; r++) accO[dt][r] *= alpha;
        }

        // exp + row sum
#pragma unroll
        for (int i = 0; i < 16; i++) p[i] = exp2f(p[i] - m_r);
        float s8[8];
#pragma unroll
        for (int i = 0; i < 8; i++) s8[i] = p[i] + p[i + 8];
#pragma unroll
        for (int st = 4; st >= 1; st >>= 1)
#pragma unroll
          for (int i = 0; i < st; i++) s8[i] += s8[i + st];
        int2v sr_ = plswap(__float_as_int(s8[0]), __float_as_int(s8[0]));
        l_r += s8[0] + __int_as_float(hi ? sr_.x : sr_.y);

        // pack P to bf16 pairs: pk[o][c] = kv_local 8o+4hi+2c, +1
        unsigned pk[4][2];
#pragma unroll
        for (int o = 0; o < 4; o++)
#pragma unroll
          for (int c = 0; c < 2; c++) {
            float lo = p[o * 4 + 2 * c];
            float hi_ = p[o * 4 + 2 * c + 1];
            asm("v_cvt_pk_bf16_f32 %0, %1, %2" : "=v"(pk[o][c]) : "v"(lo), "v"(hi_));
          }

        // PV sub: O^T += V^T_sub P^T_sub ; B-frag via permlane32_swap
#pragma unroll
        for (int ks = 0; ks < 2; ks++) {
          int2v s0 = plswap((int)pk[2 * ks][0], (int)pk[2 * ks + 1][0]);
          int2v s1 = plswap((int)pk[2 * ks][1], (int)pk[2 * ks + 1][1]);
          uint4v pw;
          pw.x = (unsigned)s0.x;   // kv_local 16ks+8hi+{0,1}
          pw.y = (unsigned)s1.x;   // +{2,3}
          pw.z = (unsigned)s0.y;   // +{4,5}
          pw.w = (unsigned)s1.y;   // +{6,7}
          short8 pb = __builtin_bit_cast(short8, pw);
          int sl = ((4 * sub + 2 * ks + hi) ^ r7) * 16;
          __builtin_amdgcn_s_setprio(1);
#pragma unroll
          for (int dt = 0; dt < 4; dt++) {
            short8 vf = *(const short8*)(Vb + dt * 32 * 128 + sl);
            accO[dt] = __builtin_amdgcn_mfma_f32_32x32x16_bf16(vf, pb, accO[dt], 0, 0, 0);
          }
          __builtin_amdgcn_s_setprio(0);
        }
      }
    }

    // ---- write unnormalized partial + (m, l) ----
    unsigned short* pp = part + (size_t)par * T_SEQ * HDIM + (size_t)q_row * HDIM + h * HD;
#pragma unroll
    for (int dt = 0; dt < 4; dt++)
#pragma unroll
      for (int q4 = 0; q4 < 4; q4++) {
        int dbase = 32 * dt + 8 * q4 + 4 * hi;
        u16x4 o;
#pragma unroll
        for (int j = 0; j < 4; j++) o[j] = f2bf(accO[dt][q4 * 4 + j]);
        *(u16x4*)(pp + dbase) = o;
      }
    if (hi == 0) {
      float* mlp = ml + ((size_t)h * T_SEQ + q_row) * 4 + par * 2;
      mlp[0] = m_r; mlp[1] = l_r;
    }
  }
}

// ---------------- flash attention pass 2: merge parity partials ----------------
// ao[q][h*128+d] = (P0*2^(m0-m) + P1*2^(m1-m)) / (l0*2^(m0-m) + l1*2^(m1-m))
// Fully-masked rows (qt=0,par=1) have m1=-1e30 -> 2^(m1-m)=0 annihilates garbage.
__global__ __launch_bounds__(256) void attn_merge(const unsigned short* __restrict__ part,
                                                  const float* __restrict__ ml,
                                                  unsigned short* __restrict__ ao) {
  int gid = blockIdx.x * 256 + threadIdx.x;     // 4096 q x 256 chunks of 8
  int q = gid >> 8, hd0 = (gid & 255) * 8;
  int h = hd0 >> 7;
  float4 m4 = *(const float4*)(ml + ((size_t)h * T_SEQ + q) * 4);  // m0,l0,m1,l1
  float m  = fmaxf(m4.x, m4.z);
  float se = exp2f(m4.x - m), so = exp2f(m4.z - m);
  float inv = 1.0f / (m4.y * se + m4.w * so);
  u16x8 a = *(const u16x8*)(part + (size_t)q * HDIM + hd0);
  u16x8 b = *(const u16x8*)(part + (size_t)T_SEQ * HDIM + (size_t)q * HDIM + hd0);
  u16x8 o;
#pragma unroll
  for (int j = 0; j < 8; j++)
    o[j] = f2bf((bf2f(a[j]) * se + bf2f(b[j]) * so) * inv);
  *(u16x8*)(ao + (size_t)q * HDIM + hd0) = o;
}

// ---------------- launch ----------------
extern "C" void kernel_launch(void* const* d_in, const int* in_sizes, int n_in,
                              void* d_out, int out_size, void* d_ws, size_t ws_size,
                              hipStream_t stream) {
  const float* x      = (const float*)d_in[0];
  const float* ve     = (const float*)d_in[1];
  const float* lam    = (const float*)d_in[2];
  const float* qkv_w  = (const float*)d_in[3];
  const float* proj_w = (const float*)d_in[4];
  float* out = (float*)d_out;

  char* p = (char*)d_ws;
  float* cosT = (float*)p;            p += (size_t)T_SEQ * 64 * 4;
  float* sinT = (float*)p;            p += (size_t)T_SEQ * 64 * 4;
  unsigned short* xb   = (unsigned short*)p; p += (size_t)T_SEQ * DIM * 2;
  unsigned short* wqb  = (unsigned short*)p; p += (size_t)3 * HDIM * DIM * 2;
  unsigned short* pwb  = (unsigned short*)p; p += (size_t)DIM * HDIM * 2;
  unsigned short* qkvb = (unsigned short*)p; p += (size_t)3 * NH * T_SEQ * HD * 2;
  unsigned short* vtb  = (unsigned short*)p; p += (size_t)NH * HD * T_SEQ * 2;
  unsigned short* aob  = (unsigned short*)p; p += (size_t)T_SEQ * HDIM * 2;
  // partials ALIAS xb+wqb (16+24=40MB, dead after the QKV GEMM; need 32+1MB):
  unsigned short* prt  = xb;
  float* mlb           = (float*)((char*)xb + (size_t)2 * T_SEQ * HDIM * 2);

  cvt_f32_bf16<<<(T_SEQ * DIM / 4 + 255) / 256, 256, 0, stream>>>(x, xb, T_SEQ * DIM / 4);
  cvt_f32_bf16<<<(3 * HDIM * DIM / 4 + 255) / 256, 256, 0, stream>>>(qkv_w, wqb, 3 * HDIM * DIM / 4);
  cvt_f32_bf16<<<(DIM * HDIM / 4 + 255) / 256, 256, 0, stream>>>(proj_w, pwb, DIM * HDIM / 4);
  rope_tables<<<(T_SEQ * 64 + 255) / 256, 256, 0, stream>>>(cosT, sinT);

  // QKV: M=4096 (32 m-blocks), N=6144 (24 n-blocks) -> 768 blocks = 3/CU exactly
  gemm256<0><<<768, 512, 0, stream>>>(xb, wqb, DIM, qkvb, nullptr, 3 * HDIM);
  norm_rope<<<2 * NH * T_SEQ / 4, 256, 0, stream>>>(qkvb, cosT, sinT);
  vmix_transpose<<<dim3(T_SEQ / 64, HD / 64, NH), 256, 0, stream>>>(
      qkvb + (size_t)2 * NH * T_SEQ * HD, ve, lam, vtb);
  // attention: 512 balanced split-KV blocks (2/CU), then elementwise merge
  attn_part<<<512, 256, 0, stream>>>(qkvb, qkvb + (size_t)NH * T_SEQ * HD, vtb, prt, mlb);
  attn_merge<<<T_SEQ * 256 / 256, 256, 0, stream>>>(prt, mlb, aob);
  // proj: M=4096 (32), N=2048 (8 n-blocks) -> 256 blocks = 1/CU exactly
  gemm256<1><<<256, 512, 0, stream>>>(aob, pwb, HDIM, nullptr, out, HDIM);
}

// Round 12
// 340.706 us; speedup vs baseline: 1.0970x; 1.0942x over previous
//
#include <hip/hip_runtime.h>
#include <cstdint>
#include <cstddef>

// ---------------- constants ----------------
constexpr int T_SEQ = 4096;
constexpr int NH    = 16;
constexpr int HD    = 128;
constexpr int DIM   = 2048;
constexpr int HDIM  = 2048;   // NH*HD

typedef __attribute__((ext_vector_type(8)))  short  short8;
typedef __attribute__((ext_vector_type(4)))  float  f32x4;
typedef __attribute__((ext_vector_type(16))) float  f32x16;
typedef __attribute__((ext_vector_type(8)))  unsigned short u16x8;
typedef __attribute__((ext_vector_type(4)))  unsigned short u16x4;
typedef __attribute__((ext_vector_type(4)))  unsigned uint4v;
typedef __attribute__((ext_vector_type(2)))  int int2v;

__device__ __forceinline__ unsigned short f2bf(float f) {
  unsigned u = __float_as_uint(f);
  return (unsigned short)((u + 0x7FFFu + ((u >> 16) & 1u)) >> 16);  // RNE
}
__device__ __forceinline__ float bf2f(unsigned short h) {
  return __uint_as_float(((unsigned)h) << 16);
}
__device__ __forceinline__ void gload_lds16(const void* g, void* l) {
  __builtin_amdgcn_global_load_lds((const __attribute__((address_space(1))) void*)g,
                                   (__attribute__((address_space(3))) void*)l, 16, 0, 0);
}
__device__ __forceinline__ int2v plswap(int a, int b) {
  return __builtin_amdgcn_permlane32_swap(a, b, false, false);
}
__device__ __forceinline__ void bar() {           // raw barrier: no implicit vmcnt(0)
  asm volatile("" ::: "memory");
  __builtin_amdgcn_s_barrier();
  asm volatile("" ::: "memory");
}
#define VMCNT(n) asm volatile("s_waitcnt vmcnt(" #n ")" ::: "memory")

// ---------------- fp32 -> bf16 convert ----------------
__global__ __launch_bounds__(256) void cvt_f32_bf16(const float* __restrict__ in,
                                                    unsigned short* __restrict__ out, int n4) {
  int i = blockIdx.x * 256 + threadIdx.x;
  if (i < n4) {
    float4 v = ((const float4*)in)[i];
    u16x4 o; o.x = f2bf(v.x); o.y = f2bf(v.y); o.z = f2bf(v.z); o.w = f2bf(v.w);
    ((u16x4*)out)[i] = o;
  }
}

// ---------------- RoPE tables ----------------
__global__ __launch_bounds__(256) void rope_tables(float* __restrict__ cosT, float* __restrict__ sinT) {
  int idx = blockIdx.x * 256 + threadIdx.x;           // T_SEQ*64
  if (idx >= T_SEQ * 64) return;
  int t = idx >> 6, i = idx & 63;
  float ang = (i < 32) ? exp2f(-10.0f * (float)i / 31.0f) : 0.0f;  // (1/1024)^(i/31)
  float th = (float)t * ang;
  cosT[idx] = cosf(th);
  sinT[idx] = sinf(th);
}

// ---------------- GEMM: C = A * B^T (deep-pipelined, T2+T3+T4+T5) ----------------
template <int MODE>
__global__ __launch_bounds__(512) void gemm256(const unsigned short* __restrict__ A,
                                               const unsigned short* __restrict__ B,
                                               int K, unsigned short* __restrict__ outb,
                                               float* __restrict__ outf, int N) {
  __shared__ __align__(16) char SM[3 * 49152];   // 144KB: 3 x [A 16KB | B 32KB]
  const int tid = threadIdx.x, w = tid >> 6, lane = tid & 63;
  const int wm = w >> 2, wn = w & 3;
  const int lr = lane >> 4, lc = lane & 15, lc7 = lc & 7;
  const int cpx = gridDim.x >> 3;
  const int idx = (blockIdx.x & 7) * cpx + (blockIdx.x >> 3);
  const int m0 = (idx & 31) * 128, n0 = (idx >> 5) * 256;

  const int arow = lane >> 3;
  const int xcol = ((lane & 7) ^ ((lane >> 3) & 7)) * 8;  // pre-swizzled source col

  auto stageA = [&](int buf, int t) {
    char* base = SM + buf * 49152;
#pragma unroll
    for (int i = 0; i < 2; i++) {
      int c = w + i * 8;
      gload_lds16(A + (size_t)(m0 + c * 8 + arow) * K + t * 64 + xcol, base + c * 1024);
    }
  };
  auto stageB0 = [&](int buf, int t) {
    char* base = SM + buf * 49152 + 16384;
    gload_lds16(B + (size_t)(n0 + w * 8 + arow) * K + t * 64 + xcol, base + w * 1024);
  };
  auto stageB1 = [&](int buf, int t) {
    char* base = SM + buf * 49152 + 16384;
#pragma unroll
    for (int i = 1; i < 4; i++) {
      int c = w + i * 8;
      gload_lds16(B + (size_t)(n0 + c * 8 + arow) * K + t * 64 + xcol, base + c * 1024);
    }
  };

  f32x4 acc[4][4] = {};
  const int NT = K >> 6;

  stageA(0, 0); stageB0(0, 0); stageB1(0, 0);
  stageA(1, 1); stageB0(1, 1); stageB1(1, 1);
  VMCNT(6);
  bar();

#pragma unroll 1
  for (int t = 0; t < NT; t++) {
    const int c = t % 3, s = (t + 2) % 3;
    const bool st = (t + 2) < NT;
    const char* Ab = SM + c * 49152;
    const char* Bb = Ab + 16384;

    short8 a[4], b[4];
#pragma unroll
    for (int mi = 0; mi < 4; mi++)
      a[mi] = *(const short8*)(Ab + (wm * 64 + mi * 16 + lc) * 128 + ((0 + lr) ^ lc7) * 16);
#pragma unroll
    for (int ni = 0; ni < 4; ni++)
      b[ni] = *(const short8*)(Bb + (wn * 64 + ni * 16 + lc) * 128 + ((0 + lr) ^ lc7) * 16);
    if (st) { stageA(s, t + 2); stageB0(s, t + 2); }
    bar();
    __builtin_amdgcn_s_setprio(1);
#pragma unroll
    for (int mi = 0; mi < 4; mi++)
#pragma unroll
      for (int ni = 0; ni < 4; ni++)
        acc[mi][ni] = __builtin_amdgcn_mfma_f32_16x16x32_bf16(a[mi], b[ni], acc[mi][ni], 0, 0, 0);
    __builtin_amdgcn_s_setprio(0);
    bar();

#pragma unroll
    for (int mi = 0; mi < 4; mi++)
      a[mi] = *(const short8*)(Ab + (wm * 64 + mi * 16 + lc) * 128 + ((4 + lr) ^ lc7) * 16);
#pragma unroll
    for (int ni = 0; ni < 4; ni++)
      b[ni] = *(const short8*)(Bb + (wn * 64 + ni * 16 + lc) * 128 + ((4 + lr) ^ lc7) * 16);
    if (st) stageB1(s, t + 2);
    if (st) { VMCNT(6); } else { VMCNT(0); }
    bar();
    __builtin_amdgcn_s_setprio(1);
#pragma unroll
    for (int mi = 0; mi < 4; mi++)
#pragma unroll
      for (int ni = 0; ni < 4; ni++)
        acc[mi][ni] = __builtin_amdgcn_mfma_f32_16x16x32_bf16(a[mi], b[ni], acc[mi][ni], 0, 0, 0);
    __builtin_amdgcn_s_setprio(0);
    bar();
  }

#pragma unroll
  for (int mi = 0; mi < 4; mi++)
#pragma unroll
    for (int ni = 0; ni < 4; ni++)
#pragma unroll
      for (int r = 0; r < 4; r++) {
        int t = m0 + wm * 64 + mi * 16 + lr * 4 + r;
        int n = n0 + wn * 64 + ni * 16 + lc;
        float v = acc[mi][ni][r];
        if (MODE == 0) {
          int cc = n >> 11, e = n & 2047, h = e >> 7, d = e & 127;
          outb[(((size_t)cc * NH + h) * T_SEQ + t) * HD + d] = f2bf(v);
        } else {
          outf[(size_t)t * N + n] = v;
        }
      }
}

// ---------------- RMSNorm + RoPE (in-place on q,k; layout [c][h][t][d]) ----------------
// Vectorized: 16 lanes/row x short8 (16B/lane, G13), shfl-tree row reduce (width 16),
// partner-half exchange via 4 dword shuffles (rs is row-uniform -> exchange raw values).
__global__ __launch_bounds__(256) void norm_rope(unsigned short* __restrict__ qkvb,
                                                 const float* __restrict__ cosT,
                                                 const float* __restrict__ sinT) {
  const int tid = threadIdx.x;
  const int li = tid & 15;                          // position within row (8 elems each)
  const int row = blockIdx.x * 16 + (tid >> 4);     // row over [c][h][t]
  const int t = row & (T_SEQ - 1);
  unsigned short* rp = qkvb + (size_t)row * HD + li * 8;
  u16x8 raw = *(const u16x8*)rp;

  float v[8]; float ss = 0.0f;
#pragma unroll
  for (int j = 0; j < 8; j++) { v[j] = bf2f(raw[j]); ss += v[j] * v[j]; }
#pragma unroll
  for (int off = 1; off < 16; off <<= 1) ss += __shfl_xor(ss, off, 16);
  const float rs = rsqrtf(ss * (1.0f / 128.0f) + 1e-6f);

  // partner (lane li^8) raw values: 4 dword shuffles
  uint4v rw = __builtin_bit_cast(uint4v, raw);
  uint4v pwv;
  pwv.x = (unsigned)__shfl_xor((int)rw.x, 8, 16);
  pwv.y = (unsigned)__shfl_xor((int)rw.y, 8, 16);
  pwv.z = (unsigned)__shfl_xor((int)rw.z, 8, 16);
  pwv.w = (unsigned)__shfl_xor((int)rw.w, 8, 16);
  u16x8 praw = __builtin_bit_cast(u16x8, pwv);
  float pv[8];
#pragma unroll
  for (int j = 0; j < 8; j++) pv[j] = bf2f(praw[j]);

  const int e0 = (li & 7) * 8;                      // angle base index (0..56)
  const bool hi8 = li >= 8;
  float4 c0 = *(const float4*)(cosT + t * 64 + e0);
  float4 c1 = *(const float4*)(cosT + t * 64 + e0 + 4);
  float4 s0 = *(const float4*)(sinT + t * 64 + e0);
  float4 s1 = *(const float4*)(sinT + t * 64 + e0 + 4);
  float cc[8] = {c0.x, c0.y, c0.z, c0.w, c1.x, c1.y, c1.z, c1.w};
  float sn[8] = {s0.x, s0.y, s0.z, s0.w, s1.x, s1.y, s1.z, s1.w};

  u16x8 o;
#pragma unroll
  for (int j = 0; j < 8; j++) {
    float x1 = hi8 ? pv[j] : v[j];                  // first-half value
    float x2 = hi8 ? v[j] : pv[j];                  // second-half value
    float r = hi8 ? (-x1 * sn[j] + x2 * cc[j]) : (x1 * cc[j] + x2 * sn[j]);
    o[j] = f2bf(r * rs);
  }
  *(u16x8*)rp = o;
}

// ---------------- v' = l0*v + l1*ve, transposed to v_t[h][d][t] ----------------
__global__ __launch_bounds__(256) void vmix_transpose(const unsigned short* __restrict__ vb,
                                                      const float* __restrict__ ve,
                                                      const float* __restrict__ lam,
                                                      unsigned short* __restrict__ vt) {
  __shared__ float tile[64][65];
  const int h = blockIdx.z, t0 = blockIdx.x * 64, d0 = blockIdx.y * 64;
  const float l0 = lam[0], l1 = lam[1];
  const int tid = threadIdx.x;
  const int tl = tid >> 4, dl4 = (tid & 15) * 4;
#pragma unroll
  for (int i = 0; i < 4; i++) {
    int t_local = tl + i * 16;
    int t = t0 + t_local;
    const unsigned short* vp = vb + ((size_t)h * T_SEQ + t) * HD + d0 + dl4;
    const float* vep = ve + (size_t)t * HDIM + h * HD + d0 + dl4;
    u16x4 vv = *(const u16x4*)vp;
    float4 vef = *(const float4*)vep;
    tile[t_local][dl4 + 0] = l0 * bf2f(vv.x) + l1 * vef.x;
    tile[t_local][dl4 + 1] = l0 * bf2f(vv.y) + l1 * vef.y;
    tile[t_local][dl4 + 2] = l0 * bf2f(vv.z) + l1 * vef.z;
    tile[t_local][dl4 + 3] = l0 * bf2f(vv.w) + l1 * vef.w;
  }
  __syncthreads();
#pragma unroll
  for (int i = 0; i < 2; i++) {
    int idx = tid + i * 256;
    int d_local = idx >> 3, tloc = (idx & 7) * 8;
    u16x8 o;
#pragma unroll
    for (int j = 0; j < 8; j++) o[j] = f2bf(tile[tloc + j][d_local]);
    *(u16x8*)(vt + ((size_t)h * HD + d0 + d_local) * T_SEQ + t0 + tloc) = o;
  }
}

// ---------------- flash attention (causal), swapped-operand 32x32x16 ----------------
// R7 version (proven 159us, Occ 21.2): 8 warps / 512 threads; kv-parity split
// (warps 0-3 even tiles, 4-7 odd) with LDS merge. Group-local monotonic LDS-counter
// barrier per iter -> the two parity groups drift phase (VALU of one overlaps
// MFMA+LDS of the other). Full block barriers only at q-tile start and combine.
__global__ __launch_bounds__(512)
__attribute__((amdgpu_waves_per_eu(2, 2)))
void attn_fwd(const unsigned short* __restrict__ qb,
              const unsigned short* __restrict__ kb,
              const unsigned short* __restrict__ vt,
              unsigned short* __restrict__ ao) {
  __shared__ __align__(16) char SMEM[131072];   // [group][ K 2x16KB | V 2x16KB ]
  __shared__ int gctr[2];                       // group-barrier monotonic counters
  const int bid = blockIdx.x;
  const int h  = (bid & 7) + ((bid >> 7) << 3);  // XCD swizzle: head h on XCD h%8
  const int pr = (bid >> 3) & 15;
  const int tid = threadIdx.x, w = tid >> 6, lane = tid & 63;
  const int g = w >> 2, wq = w & 3;
  const int l31 = lane & 31, hi = lane >> 5, r7 = l31 & 7;
  const unsigned short* qh = qb + (size_t)h * T_SEQ * HD;
  const unsigned short* kh = kb + (size_t)h * T_SEQ * HD;
  const unsigned short* vh = vt + (size_t)h * HD * T_SEQ;

  if (tid < 2) gctr[tid] = 0;
  __syncthreads();
  int bcnt = 0;
  auto GBAR = [&]() {   // group-local barrier: 4 waves of group g
    asm volatile("s_waitcnt lgkmcnt(0)" ::: "memory");
    ++bcnt;
    if (lane == 0)
      __hip_atomic_fetch_add(&gctr[g], 1, __ATOMIC_RELEASE, __HIP_MEMORY_SCOPE_WORKGROUP);
    while (__hip_atomic_load(&gctr[g], __ATOMIC_ACQUIRE, __HIP_MEMORY_SCOPE_WORKGROUP) < 4 * bcnt)
      __builtin_amdgcn_s_sleep(1);
  };

  char* Kbase = SMEM + g * 65536;
  char* Vbase = SMEM + g * 65536 + 32768;

  const int kcrow = lane >> 4, kcol16 = lane & 15;   // K staging: 4 rows / 1KB chunk
  const int vcrow = lane >> 3, vslot0 = lane & 7;    // V staging: 8 rows / 1KB chunk

  auto STAGE = [&](int buf, int t) {                 // t = global kv tile index
#pragma unroll
    for (int i = 0; i < 4; i++) {
      int krow = (wq * 4 + i) * 4 + kcrow;
      int kcol = (kcol16 ^ (krow & 7)) * 8;          // pre-swizzled source (rule #21)
      gload_lds16(kh + (size_t)(t * 64 + krow) * HD + kcol,
                  Kbase + buf * 16384 + (wq * 4 + i) * 1024);
      int vrow = (wq * 4 + i) * 8 + vcrow;
      int vcol = (vslot0 ^ (vrow & 7)) * 8;
      gload_lds16(vh + (size_t)vrow * T_SEQ + t * 64 + vcol,
                  Vbase + buf * 16384 + (wq * 4 + i) * 1024);
    }
  };

  const float SCL2E = 0.088388347648318447f * 1.44269504f;  // 1/sqrt(128) * log2(e)

#pragma unroll 1
  for (int which = 0; which < 2; ++which) {
    const int qt = which ? pr : (31 - pr);     // heavy tile first
    const int ng = qt + 1;                     // tiles for THIS group (parity g)
    const int q_row = qt * 128 + wq * 32 + l31;

    short8 qf[8];                              // B-frag: Q[q_row][16dk + 8hi + 0..7]
#pragma unroll
    for (int dk = 0; dk < 8; dk++)
      qf[dk] = *(const short8*)(qh + (size_t)q_row * HD + dk * 16 + hi * 8);

    f32x16 accO[4] = {};                       // O^T: col=q, rows d (4 tiles of 32)
    float m_r = -1e30f, l_r = 0.0f;

    __syncthreads();                           // prev combine reads done (cross-group)
    STAGE(0, g);

#pragma unroll 1
    for (int it = 0; it < ng; it++) {
      const int t = 2 * it + g;                // this group's kv tile
      const int cur = it & 1;
      asm volatile("s_waitcnt vmcnt(0)" ::: "memory");  // own stage(cur) landed
      GBAR();                                           // group's stage(cur) landed
      if (it + 1 < ng) STAGE(cur ^ 1, t + 2);           // prefetch under compute

      // ---- S^T = K Q^T : 2 kv-subtiles x 8 d-steps ----
      f32x16 accS0 = {}, accS1 = {};
      const char* Kb = Kbase + cur * 16384 + l31 * 256;
      __builtin_amdgcn_s_setprio(1);
#pragma unroll
      for (int dk = 0; dk < 8; dk++) {
        int sl = ((2 * dk + hi) ^ r7) * 16;
        short8 k0 = *(const short8*)(Kb + sl);
        short8 k1 = *(const short8*)(Kb + 32 * 256 + sl);
        accS0 = __builtin_amdgcn_mfma_f32_32x32x16_bf16(k0, qf[dk], accS0, 0, 0, 0);
        accS1 = __builtin_amdgcn_mfma_f32_32x32x16_bf16(k1, qf[dk], accS1, 0, 0, 0);
      }
      __builtin_amdgcn_s_setprio(0);

      // ---- scale + causal mask; lane holds P[q_row][kv], kv = 64t+(r&3)+8(r>>2)+4hi ----
      float p[32];
      const bool need_mask = (t * 64 + 63) > (qt * 128 + wq * 32);
      if (need_mask) {
#pragma unroll
        for (int r = 0; r < 16; r++) {
          int kv0 = t * 64 + (r & 3) + 8 * (r >> 2) + 4 * hi;
          p[r]      = (kv0      > q_row) ? -1e30f : accS0[r] * SCL2E;
          p[16 + r] = (kv0 + 32 > q_row) ? -1e30f : accS1[r] * SCL2E;
        }
      } else {
#pragma unroll
        for (int r = 0; r < 16; r++) { p[r] = accS0[r] * SCL2E; p[16 + r] = accS1[r] * SCL2E; }
      }

      // ---- row max: in-register tree + one cross-half permlane ----
      float t16[16];
#pragma unroll
      for (int i = 0; i < 16; i++) t16[i] = fmaxf(p[i], p[i + 16]);
#pragma unroll
      for (int st = 8; st >= 1; st >>= 1)
#pragma unroll
        for (int i = 0; i < st; i++) t16[i] = fmaxf(t16[i], t16[i + st]);
      int2v mr_ = plswap(__float_as_int(t16[0]), __float_as_int(t16[0]));
      float mx = fmaxf(t16[0], __int_as_float(hi ? mr_.x : mr_.y));

      // ---- defer-max (T13): rescale only when max grows past THR ----
      if (__any(mx > m_r + 8.0f)) {
        float mn = fmaxf(m_r, mx);
        float alpha = exp2f(m_r - mn);
        m_r = mn; l_r *= alpha;
#pragma unroll
        for (int dt = 0; dt < 4; dt++)
#pragma unroll
          for (int r = 0; r < 16; r++) accO[dt][r] *= alpha;
      }

      // ---- exp + row sum ----
#pragma unroll
      for (int i = 0; i < 32; i++) p[i] = exp2f(p[i] - m_r);
      float s16[16];
#pragma unroll
      for (int i = 0; i < 16; i++) s16[i] = p[i] + p[i + 16];
#pragma unroll
      for (int st = 8; st >= 1; st >>= 1)
#pragma unroll
        for (int i = 0; i < st; i++) s16[i] += s16[i + st];
      int2v sr_ = plswap(__float_as_int(s16[0]), __float_as_int(s16[0]));
      l_r += s16[0] + __int_as_float(hi ? sr_.x : sr_.y);

      // ---- pack P to bf16 pairs: pk[octet][c] = (kv=8o+4hi+2c, +1) ----
      unsigned pk[8][2];
#pragma unroll
      for (int o = 0; o < 8; o++)
#pragma unroll
        for (int c = 0; c < 2; c++) {
          float lo = p[(o >> 2) * 16 + (o & 3) * 4 + 2 * c];
          float hi_ = p[(o >> 2) * 16 + (o & 3) * 4 + 2 * c + 1];
          asm("v_cvt_pk_bf16_f32 %0, %1, %2" : "=v"(pk[o][c]) : "v"(lo), "v"(hi_));
        }

      // ---- PV: O^T += V^T P^T ; B-frag(ks) via permlane32_swap (VALU, dual-output) ----
      const char* Vb = Vbase + cur * 16384 + l31 * 128;
#pragma unroll
      for (int ks = 0; ks < 4; ks++) {
        int2v s0 = plswap((int)pk[2 * ks][0], (int)pk[2 * ks + 1][0]);
        int2v s1 = plswap((int)pk[2 * ks][1], (int)pk[2 * ks + 1][1]);
        uint4v pw;
        pw.x = (unsigned)s0.x;   // kv 16ks+8hi+{0,1}
        pw.y = (unsigned)s1.x;   // +{2,3}
        pw.z = (unsigned)s0.y;   // +{4,5}
        pw.w = (unsigned)s1.y;   // +{6,7}
        short8 pb = __builtin_bit_cast(short8, pw);
        int sl = ((2 * ks + hi) ^ r7) * 16;
        __builtin_amdgcn_s_setprio(1);
#pragma unroll
        for (int dt = 0; dt < 4; dt++) {
          short8 vf = *(const short8*)(Vb + dt * 32 * 128 + sl);
          accO[dt] = __builtin_amdgcn_mfma_f32_32x32x16_bf16(vf, pb, accO[dt], 0, 0, 0);
        }
        __builtin_amdgcn_s_setprio(0);
      }
    }

    // ---- combine even/odd partials, even group writes output ----
    __syncthreads();                                  // all compute done (cross-group)
    float* SM_acc = (float*)(SMEM + 65536);           // odd group's staging (dead now)
    float* SM_ml  = (float*)SMEM;                     // even group's staging (dead now)
    const int q_local = wq * 32 + l31;
    if (g == 1) {
#pragma unroll
      for (int dt = 0; dt < 4; dt++)
#pragma unroll
        for (int r = 0; r < 16; r++) {
          int d = 32 * dt + (r & 3) + 8 * (r >> 2) + 4 * hi;
          SM_acc[q_local * 128 + (d ^ l31)] = accO[dt][r];   // word-swz: conflict-free
        }
      if (hi == 0) { SM_ml[q_local * 2] = m_r; SM_ml[q_local * 2 + 1] = l_r; }
    }
    __syncthreads();                                  // partials visible
    if (g == 0) {
      float mo = SM_ml[q_local * 2], lo = SM_ml[q_local * 2 + 1];
      float m  = fmaxf(m_r, mo);
      float se = exp2f(m_r - m), so = exp2f(mo - m);
      float inv = 1.0f / (l_r * se + lo * so);
#pragma unroll
      for (int dt = 0; dt < 4; dt++)
#pragma unroll
        for (int q4 = 0; q4 < 4; q4++) {
          int dbase = 32 * dt + 8 * q4 + 4 * hi;
          u16x4 o;
#pragma unroll
          for (int j = 0; j < 4; j++) {
            int r = q4 * 4 + j, d = dbase + j;
            float vo = SM_acc[q_local * 128 + (d ^ l31)];
            o[j] = f2bf((accO[dt][r] * se + vo * so) * inv);
          }
          *(u16x4*)(ao + (size_t)q_row * HDIM + h * HD + dbase) = o;
        }
    }
  }
}

// ---------------- launch ----------------
extern "C" void kernel_launch(void* const* d_in, const int* in_sizes, int n_in,
                              void* d_out, int out_size, void* d_ws, size_t ws_size,
                              hipStream_t stream) {
  const float* x      = (const float*)d_in[0];
  const float* ve     = (const float*)d_in[1];
  const float* lam    = (const float*)d_in[2];
  const float* qkv_w  = (const float*)d_in[3];
  const float* proj_w = (const float*)d_in[4];
  float* out = (float*)d_out;

  char* p = (char*)d_ws;
  float* cosT = (float*)p;            p += (size_t)T_SEQ * 64 * 4;
  float* sinT = (float*)p;            p += (size_t)T_SEQ * 64 * 4;
  unsigned short* xb   = (unsigned short*)p; p += (size_t)T_SEQ * DIM * 2;
  unsigned short* wqb  = (unsigned short*)p; p += (size_t)3 * HDIM * DIM * 2;
  unsigned short* pwb  = (unsigned short*)p; p += (size_t)DIM * HDIM * 2;
  unsigned short* qkvb = (unsigned short*)p; p += (size_t)3 * NH * T_SEQ * HD * 2;
  unsigned short* vtb  = (unsigned short*)p; p += (size_t)NH * HD * T_SEQ * 2;
  unsigned short* aob  = (unsigned short*)p; p += (size_t)T_SEQ * HDIM * 2;

  cvt_f32_bf16<<<(T_SEQ * DIM / 4 + 255) / 256, 256, 0, stream>>>(x, xb, T_SEQ * DIM / 4);
  cvt_f32_bf16<<<(3 * HDIM * DIM / 4 + 255) / 256, 256, 0, stream>>>(qkv_w, wqb, 3 * HDIM * DIM / 4);
  cvt_f32_bf16<<<(DIM * HDIM / 4 + 255) / 256, 256, 0, stream>>>(proj_w, pwb, DIM * HDIM / 4);
  rope_tables<<<(T_SEQ * 64 + 255) / 256, 256, 0, stream>>>(cosT, sinT);

  // QKV: M=4096 (32 m-blocks), N=6144 (24 n-blocks) -> 768 blocks = 3/CU exactly
  gemm256<0><<<768, 512, 0, stream>>>(xb, wqb, DIM, qkvb, nullptr, 3 * HDIM);
  norm_rope<<<2 * NH * T_SEQ / 16, 256, 0, stream>>>(qkvb, cosT, sinT);
  vmix_transpose<<<dim3(T_SEQ / 64, HD / 64, NH), 256, 0, stream>>>(
      qkvb + (size_t)2 * NH * T_SEQ * HD, ve, lam, vtb);
  attn_fwd<<<256, 512, 0, stream>>>(qkvb, qkvb + (size_t)NH * T_SEQ * HD, vtb, aob);
  // proj: M=4096 (32), N=2048 (8 n-blocks) -> 256 blocks = 1/CU exactly
  gemm256<1><<<256, 512, 0, stream>>>(aob, pwb, HDIM, nullptr, out, HDIM);
}